// Round 13
// baseline (133.372 us; speedup 1.0000x reference)
//
#include <hip/hip_runtime.h>
#include <hip/hip_bf16.h>
#include <hip/hip_fp8.h>

typedef __attribute__((ext_vector_type(2))) float f32x2;
typedef __attribute__((ext_vector_type(4))) int i32x4;
typedef __attribute__((ext_vector_type(8))) int i32x8;
typedef __attribute__((ext_vector_type(16))) float f32x16;

#define MARGIN 0.3f
#define BIGF 3.0e38f

#if defined(__has_builtin)
#if __has_builtin(__builtin_amdgcn_cvt_pk_fp8_f32) && \
    __has_builtin(__builtin_amdgcn_cvt_pk_f32_fp8)
#define HAVE_PK_FP8 1
#endif
#endif

__device__ __forceinline__ void gl2lds16(const void* g, void* l) {
    __builtin_amdgcn_global_load_lds(
        (const __attribute__((address_space(1))) void*)g,
        (__attribute__((address_space(3))) void*)l,
        16, 0, 0);
}

// Wave-per-row convert: fp32 -> fp8 e4m3 (OCP) cast, fp32 row norm of the
// fp8-ROUNDED values (consistent with MFMA dots -> exact diagonal), init
// ap/an/cnt. Packed v_cvt_pk_* path when available (guarded; ctor fallback
// is the R7-R12-verified code).
__global__ __launch_bounds__(256) void convert_norm_kernel(
    const float* __restrict__ X, unsigned char* __restrict__ Xq,
    float* __restrict__ nrm, unsigned* __restrict__ ap,
    unsigned* __restrict__ an, unsigned* __restrict__ cnt, int K) {
    const int wave = threadIdx.x >> 6, lane = threadIdx.x & 63;
    const int row = blockIdx.x * 4 + wave;
    const float* xr = X + (size_t)row * K;
    unsigned char* xqr = Xq + (size_t)row * K;
    float s = 0.0f;
    for (int c = lane * 8; c < K; c += 64 * 8) {
        float4 v0 = *(const float4*)(xr + c);
        float4 v1 = *(const float4*)(xr + c + 4);
#if defined(HAVE_PK_FP8)
        int w0 = 0, w1 = 0;
        w0 = __builtin_amdgcn_cvt_pk_fp8_f32(v0.x, v0.y, w0, false);
        w0 = __builtin_amdgcn_cvt_pk_fp8_f32(v0.z, v0.w, w0, true);
        w1 = __builtin_amdgcn_cvt_pk_fp8_f32(v1.x, v1.y, w1, false);
        w1 = __builtin_amdgcn_cvt_pk_fp8_f32(v1.z, v1.w, w1, true);
        f32x2 d0 = __builtin_amdgcn_cvt_pk_f32_fp8(w0, false);
        f32x2 d1 = __builtin_amdgcn_cvt_pk_f32_fp8(w0, true);
        f32x2 d2 = __builtin_amdgcn_cvt_pk_f32_fp8(w1, false);
        f32x2 d3 = __builtin_amdgcn_cvt_pk_f32_fp8(w1, true);
        s += d0[0]*d0[0] + d0[1]*d0[1] + d1[0]*d1[0] + d1[1]*d1[1];
        s += d2[0]*d2[0] + d2[1]*d2[1] + d3[0]*d3[0] + d3[1]*d3[1];
        uint2 u; u.x = (unsigned)w0; u.y = (unsigned)w1;
        *(uint2*)(xqr + c) = u;
#else
        float f[8] = {v0.x, v0.y, v0.z, v0.w, v1.x, v1.y, v1.z, v1.w};
        union { unsigned char b[8]; uint2 u; } p;
#pragma unroll
        for (int i = 0; i < 8; i++) {
            __hip_fp8_e4m3 q(f[i]);       // OCP e4m3, RNE+saturate
            p.b[i] = q.__x;
            float d = (float)q;           // decoded value
            s += d * d;
        }
        *(uint2*)(xqr + c) = p.u;
#endif
    }
    for (int off = 32; off > 0; off >>= 1) s += __shfl_xor(s, off, 64);
    if (lane == 0) {
        nrm[row] = s;
        ap[row] = 0u;           // dist_ap >= 0 always (self is a positive)
        an[row] = 0x7F800000u;  // +inf
        if (row == 0) *cnt = 0u;
    }
}

// UPPER-TRIANGLE fp8-MX GEMM-reduce at the R12-verified 128x128 shape:
// 528 blocks (r <= j tiles) -> 2 full generations + 16-block tail at
// ~16.2 us/block-slot (R1/R2 showed slot time holds at ~2 blocks/CU in
// this 2-barrier structure), vs R12's 4 generations for 1.94x the FLOPs.
// Main loop BYTE-IDENTICAL to R12 (21% MfmaUtil, verified exact): 4 waves
// (2x2), wave tile 64x64 = 2x2 subtiles of mfma_scale_f32_32x32x64_f8f6f4
// (unit scales 0x7F), BK=128, gl2lds + XOR swizzle (phys 16B chunk =
// logical ^ (row&7)). Epilogue reduces BOTH directions (rows ->
// ap/an[rowBase+..], cols -> ap/an[colBase+..]); diagonal tiles
// double-update idempotently. LAST block computes the loss.
__global__ __launch_bounds__(256, 4) void gemm_reduce_kernel(
    const unsigned char* __restrict__ Xq, const float* __restrict__ nrm,
    const int* __restrict__ Y, unsigned* __restrict__ ap,
    unsigned* __restrict__ an, unsigned* __restrict__ cnt,
    float* __restrict__ out, int N, int K) {
    __shared__ __align__(16) unsigned char sA[128 * 128];  // 16 KB
    __shared__ __align__(16) unsigned char sB[128 * 128];  // 16 KB
    __shared__ int sYr[128], sYc[128];
    __shared__ float sNr[128], sNc[128];
    __shared__ float redmax[4][64], redmin[4][64];      // row-side (wave)
    __shared__ float credmax[2][2][64], credmin[2][2][64];  // col-side [wr][wc]
    __shared__ float lsum[4];
    __shared__ unsigned s_done;

    const int tid = threadIdx.x;
    const int wave = tid >> 6;
    const int lane = tid & 63;
    const int m = lane & 31;   // row within 32x32 subtile / col within subtile
    const int h = lane >> 5;   // k-half (inputs) / row-group (outputs)
    const int wr = wave >> 1;  // wave row (0..1): rows wr*64..+63
    const int wc = wave & 1;   // wave col (0..1): cols wc*64..+63

    // Upper-triangle decode (r <= j): blocks for col-super j start at
    // j(j+1)/2; 528 total for NB=32.
    int j = 0;
    {
        const int b = blockIdx.x;
        while ((j + 1) * (j + 2) / 2 <= b) j++;
    }
    const int r = blockIdx.x - j * (j + 1) / 2;  // 0..j
    const int rowBase = r * 128;
    const int colBase = j * 128;

    if (tid < 128) {
        sYr[tid] = Y[rowBase + tid];
        sNr[tid] = nrm[rowBase + tid];
    } else {
        int t = tid - 128;
        sYc[t] = Y[colBase + t];
        sNc[t] = nrm[colBase + t];
    }

    f32x16 acc[2][2];
#pragma unroll
    for (int si = 0; si < 2; si++)
#pragma unroll
        for (int sj = 0; sj < 2; sj++)
#pragma unroll
            for (int rr = 0; rr < 16; rr++) acc[si][sj][rr] = 0.0f;

    // Staging (R12-verified): lane l covers LDS row l>>3 of an 8-row group,
    // physical 16B chunk l&7, fetching LOGICAL chunk (l&7)^(l>>3) so
    // phys = logical ^ (row&7). Each wave stages 32 rows of A and of B.
    const int rsub = lane >> 3;
    const int jchunk = (lane & 7) ^ rsub;
    const unsigned char* gA = Xq + (size_t)(rowBase + wave * 32 + rsub) * K + jchunk * 16;
    const unsigned char* gB = Xq + (size_t)(colBase + wave * 32 + rsub) * K + jchunk * 16;
    unsigned char* lA = sA + wave * 4096;  // 32 rows * 128 B
    unsigned char* lB = sB + wave * 4096;
    const size_t g8 = (size_t)8 * K;  // 8 rows, bytes

    const int e = m & 7;     // unswizzle key: row&7 = m&7 (row offsets mult of 32)
    const int nit = K >> 7;  // BK=128 (16 iters at K=2048)

    for (int it = 0; it < nit; it++) {
        const size_t go = (size_t)it * 128;  // 128 k-elems * 1 B
#pragma unroll
        for (int g = 0; g < 4; g++) {
            gl2lds16(gA + go + g * g8, lA + g * 1024);
            gl2lds16(gB + go + g * g8, lB + g * 1024);
        }
        __syncthreads();  // drains vmcnt for gl2lds

#pragma unroll
        for (int s = 0; s < 2; s++) {      // two k64 steps per BK=128
            const int c0 = s * 4 + h * 2;  // logical 16B chunk of this k-half
            i32x8 af[2], bf[2];
#pragma unroll
            for (int si = 0; si < 2; si++) {
                const unsigned char* base = sA + (wr * 64 + si * 32 + m) * 128;
                i32x4 lo = *(const i32x4*)(base + ((c0 ^ e) * 16));
                i32x4 hi = *(const i32x4*)(base + (((c0 + 1) ^ e) * 16));
                af[si] = __builtin_shufflevector(lo, hi, 0, 1, 2, 3, 4, 5, 6, 7);
            }
#pragma unroll
            for (int sj = 0; sj < 2; sj++) {
                const unsigned char* base = sB + (wc * 64 + sj * 32 + m) * 128;
                i32x4 lo = *(const i32x4*)(base + ((c0 ^ e) * 16));
                i32x4 hi = *(const i32x4*)(base + (((c0 + 1) ^ e) * 16));
                bf[sj] = __builtin_shufflevector(lo, hi, 0, 1, 2, 3, 4, 5, 6, 7);
            }
#pragma unroll
            for (int si = 0; si < 2; si++)
#pragma unroll
                for (int sj = 0; sj < 2; sj++)
                    acc[si][sj] = __builtin_amdgcn_mfma_scale_f32_32x32x64_f8f6f4(
                        af[si], bf[sj], acc[si][sj], 0 /*A fmt fp8*/,
                        0 /*B fmt fp8*/, 0, 127 /*scale A = 2^0*/,
                        0, 127 /*scale B = 2^0*/);
        }
        __syncthreads();  // protect single buffer before restage
    }

    // Epilogue, both directions. C/D: col (within subtile) = m,
    // row64 (within wave's 64 rows) = si*32 + (reg&3) + 8*(reg>>2) + 4*h.
    float cmx0 = -1.0f, cmx1 = -1.0f, cmn0 = BIGF, cmn1 = BIGF;  // per sj

#pragma unroll
    for (int si = 0; si < 2; si++)
#pragma unroll
        for (int reg = 0; reg < 16; reg++) {
            const int row64 = si * 32 + (reg & 3) + 8 * (reg >> 2) + 4 * h;
            const int rIdx = wr * 64 + row64;  // row within block tile
            const int yr = sYr[rIdx];
            const float nr = sNr[rIdx];
            float dp = -1.0f, dn = BIGF;
            {  // sj = 0
                const int cIdx = wc * 64 + m;
                float d2 = nr + sNc[cIdx] - 2.0f * acc[si][0][reg];
                float d = sqrtf(fmaxf(d2, 0.0f));
                bool same = (yr == sYc[cIdx]);
                float p = same ? d : -1.0f;
                float n = same ? BIGF : d;
                dp = fmaxf(dp, p); dn = fminf(dn, n);
                cmx0 = fmaxf(cmx0, p); cmn0 = fminf(cmn0, n);
            }
            {  // sj = 1
                const int cIdx = wc * 64 + 32 + m;
                float d2 = nr + sNc[cIdx] - 2.0f * acc[si][1][reg];
                float d = sqrtf(fmaxf(d2, 0.0f));
                bool same = (yr == sYc[cIdx]);
                float p = same ? d : -1.0f;
                float n = same ? BIGF : d;
                dp = fmaxf(dp, p); dn = fminf(dn, n);
                cmx1 = fmaxf(cmx1, p); cmn1 = fminf(cmn1, n);
            }
            // Row-side: reduce over the 32 col-lanes (offsets 1..16 keep h).
            for (int off = 1; off < 32; off <<= 1) {
                dp = fmaxf(dp, __shfl_xor(dp, off, 64));
                dn = fminf(dn, __shfl_xor(dn, off, 64));
            }
            if (m == 0) {  // lanes 0 (h=0) and 32 (h=1): disjoint row64 sets
                redmax[wave][row64] = dp;
                redmin[wave][row64] = dn;
            }
        }

    // Col-side: merge the two h row-groups (xor 32); h==0 lanes then hold
    // the extremum over this wave's 64 rows for col sj*32+m.
    {
        float mx = fmaxf(cmx0, __shfl_xor(cmx0, 32, 64));
        float mn = fminf(cmn0, __shfl_xor(cmn0, 32, 64));
        if (h == 0) { credmax[wr][wc][m] = mx; credmin[wr][wc][m] = mn; }
        mx = fmaxf(cmx1, __shfl_xor(cmx1, 32, 64));
        mn = fminf(cmn1, __shfl_xor(cmn1, 32, 64));
        if (h == 0) { credmax[wr][wc][32 + m] = mx; credmin[wr][wc][32 + m] = mn; }
    }
    __syncthreads();

    // Combine and emit atomics. Non-negative floats: uint cmp == float cmp;
    // clamp max to 0 (true dist_ap >= 0 via the diagonal self-pair).
    if (tid < 128) {
        const int g2 = tid >> 6, i64 = tid & 63;
        // Row-side: combine the two wc waves of row-half g2.
        float mx = fmaxf(redmax[g2 * 2][i64], redmax[g2 * 2 + 1][i64]);
        float mn = fminf(redmin[g2 * 2][i64], redmin[g2 * 2 + 1][i64]);
        atomicMax(&ap[rowBase + tid], __float_as_uint(fmaxf(mx, 0.0f)));
        atomicMin(&an[rowBase + tid], __float_as_uint(mn));
        // Col-side: combine the two wr waves of col-half g2.
        float cx = fmaxf(credmax[0][g2][i64], credmax[1][g2][i64]);
        float cn = fminf(credmin[0][g2][i64], credmin[1][g2][i64]);
        atomicMax(&ap[colBase + tid], __float_as_uint(fmaxf(cx, 0.0f)));
        atomicMin(&an[colBase + tid], __float_as_uint(cn));
    }

    // Last block computes the loss (release fence before counter increment;
    // acquire fence + agent-scope atomic loads in the last block).
    __syncthreads();
    if (tid == 0) {
        __threadfence();
        s_done = atomicAdd(cnt, 1u);
    }
    __syncthreads();
    if (s_done == gridDim.x - 1) {
        __threadfence();
        float s = 0.0f;
        for (int i = tid; i < N; i += 256) {
            unsigned ua = __hip_atomic_load(&ap[i], __ATOMIC_RELAXED,
                                            __HIP_MEMORY_SCOPE_AGENT);
            unsigned ub = __hip_atomic_load(&an[i], __ATOMIC_RELAXED,
                                            __HIP_MEMORY_SCOPE_AGENT);
            s += fmaxf(__uint_as_float(ua) - __uint_as_float(ub) + MARGIN, 0.0f);
        }
        for (int off = 32; off > 0; off >>= 1) s += __shfl_xor(s, off, 64);
        if (lane == 0) lsum[wave] = s;
        __syncthreads();
        if (tid == 0)
            out[0] = (lsum[0] + lsum[1] + lsum[2] + lsum[3]) / (float)N;
    }
}

extern "C" void kernel_launch(void* const* d_in, const int* in_sizes, int n_in,
                              void* d_out, int out_size, void* d_ws, size_t ws_size,
                              hipStream_t stream) {
    const float* X = (const float*)d_in[0];
    const int* Y = (const int*)d_in[1];
    float* out = (float*)d_out;
    const int N = in_sizes[1];          // 4096
    const int K = in_sizes[0] / N;      // 2048

    char* ws = (char*)d_ws;
    unsigned char* Xq = (unsigned char*)ws;                         // N*K bytes
    float* nrm = (float*)(ws + (size_t)N * K);
    unsigned* ap = (unsigned*)((char*)nrm + (size_t)N * 4);
    unsigned* an = (unsigned*)((char*)ap + (size_t)N * 4);
    unsigned* cnt = (unsigned*)((char*)an + (size_t)N * 4);

    convert_norm_kernel<<<N / 4, 256, 0, stream>>>(X, Xq, nrm, ap, an, cnt, K);
    const int NB = N / 128;
    const int nblocks = NB * (NB + 1) / 2;  // 528 upper-triangle 128x128 tiles
    gemm_reduce_kernel<<<nblocks, 256, 0, stream>>>(Xq, nrm, Y, ap, an, cnt,
                                                    out, N, K);
}